// Round 10
// baseline (341.556 us; speedup 1.0000x reference)
//
#include <hip/hip_runtime.h>
#include <hip/hip_cooperative_groups.h>

namespace cg = cooperative_groups;

typedef unsigned short u16;
typedef unsigned int u32;
typedef __attribute__((ext_vector_type(8))) short bf16x8;
typedef __attribute__((ext_vector_type(4))) float f32x4;

#define NJ 4094

__device__ __forceinline__ u16 f2bf(float f) {
  union { float f; unsigned u; } v;
  v.f = f;
  unsigned r = v.u + 0x7fffu + ((v.u >> 16) & 1u);
  return (u16)(r >> 16);
}

// pack hi16(a),hi16(b) -> u32 (a in low half), +0x8000 round-half-up pre-added
__device__ __forceinline__ u32 pk_bf(float a, float b) {
  u32 ua = __float_as_uint(a) + 0x8000u;
  u32 ub = __float_as_uint(b) + 0x8000u;
  return __builtin_amdgcn_perm(ub, ua, 0x07060302u);
}

// ============ single cooperative kernel: conv -> gridsync -> fused -> gridsync -> reduce ====
// grid (64,16) = 1024 blocks, 256 thr, LDS union 36864 B, VGPR capped by (256,4)
// => exactly 4 blocks/CU co-resident (coop-launch requirement satisfied by construction).
__global__ __launch_bounds__(256, 4) void mono_kernel(
    const float* __restrict__ x, const float* __restrict__ w,
    const float* __restrict__ bias, u16* __restrict__ x2n, u16* __restrict__ x2T,
    u16* __restrict__ x1T, u16* __restrict__ part, float* __restrict__ out) {
  __shared__ __align__(16) char smem[36864];
  const int t = threadIdx.x;
  const int flat = blockIdx.y * 64 + blockIdx.x;   // 0..1023

  // ---------------- stage A: dilated conv1d, c-split so LDS fits the union ----------------
  // block = (b, jt 16-j window, ch half of out-channels); also emits x1T (b=1 negated)
  {
    float* xs = (float*)smem;            // [64 in][20 window]  5120 B
    float* wl = xs + 64 * 20;            // [64 in][32 out][3] 24576 B
    const int b = flat >> 9, jt = (flat >> 1) & 255, ch = flat & 1;
    for (int idx = t; idx < 64 * 20; idx += 256) {
      int i = idx / 20, p = idx - i * 20;
      int jg = jt * 16 - 1 + p;
      xs[idx] = (jg >= 0 && jg < 4096) ? x[(b * 64 + i) * 4096 + jg] : 0.f;
    }
    for (int idx = t; idx < 32 * 64 * 3; idx += 256) {
      int tap = idx % 3, rest = idx / 3;
      int co = rest >> 6, i = rest & 63;
      wl[(i * 32 + co) * 3 + tap] = w[((ch * 32 + co) * 64 + i) * 3 + tap];
    }
    __syncthreads();
    if (ch == 0) {   // x1T [b][i][c], b=1 sign-flipped (folds S0-S1 into MFMA chain)
      for (int idx = t; idx < 16 * 64; idx += 256) {
        int ii = idx >> 6, ic = idx & 63;
        float v = xs[ic * 20 + ii + 1];
        x1T[(b * 4096 + jt * 16 + ii) * 64 + ic] = f2bf(b ? -v : v);
      }
    }
    const int co = t & 31, jsub = t >> 5;   // 8 jsubs x 2 j each
    const int c = ch * 32 + co;
    float a0 = bias[c], a1 = a0;
    for (int i = 0; i < 64; i++) {
      float w0 = wl[(i * 32 + co) * 3 + 0];
      float w1 = wl[(i * 32 + co) * 3 + 1];
      float w2 = wl[(i * 32 + co) * 3 + 2];
      const float* xr = &xs[i * 20 + jsub * 2];
      a0 += w0 * xr[0] + w1 * xr[2] + w2 * xr[4];
      a1 += w0 * xr[1] + w1 * xr[3] + w2 * xr[5];
    }
    int jg0 = jt * 16 + jsub * 2;
    u16 h0 = f2bf(jg0 < NJ ? a0 : 0.f);
    u16 h1 = f2bf(jg0 + 1 < NJ ? a1 : 0.f);
    x2n[(b * 64 + c) * 4096 + jg0] = h0;
    x2n[(b * 64 + c) * 4096 + jg0 + 1] = h1;
    x2T[(b * 4096 + jg0) * 64 + c] = h0;
    x2T[(b * 4096 + jg0 + 1) * 64 + c] = h1;
  }
  cg::this_grid().sync();

  // ---------------- stage B: fused S->sigmoid->PV (R9 structure, UNCHANGED inner loop;
  // do NOT re-add the unroll+prefetch pipeline: R5/R7 spill signature FETCH 9->55 MB) -----
  {
    u16 (*P)[2 * 64 * 72] = (u16(*)[2 * 64 * 72])smem;   // [buf][b*64+i][j64 pad72]
    const int wave = t >> 6, lane = t & 63;
    const int q = lane >> 4, ln = lane & 15;
    const int i0 = blockIdx.x * 64;
    const int jc = blockIdx.y;

    bf16x8 b1[2][4][2];
#pragma unroll
    for (int b = 0; b < 2; b++)
#pragma unroll
      for (int ist = 0; ist < 4; ist++)
#pragma unroll
        for (int kc = 0; kc < 2; kc++)
          b1[b][ist][kc] = *(const bf16x8*)&x1T[(b * 4096 + i0 + ist * 16 + ln) * 64 + kc * 32 + q * 8];

    f32x4 acc[2][4];
#pragma unroll
    for (int a = 0; a < 2; a++)
#pragma unroll
      for (int bq = 0; bq < 4; bq++) acc[a][bq] = (f32x4){0.f, 0.f, 0.f, 0.f};

    const int b2 = wave >> 1, cs2 = (wave & 1) * 2;

    for (int jt = jc * 4; jt < jc * 4 + 4; jt++) {
      const int j0 = jt * 64;
      u16* Ps = P[jt & 1];
      f32x4 ps[4];
#pragma unroll
      for (int ist = 0; ist < 4; ist++) ps[ist] = (f32x4){0.f, 0.f, 0.f, 0.f};
#pragma unroll
      for (int b = 0; b < 2; b++)
#pragma unroll
        for (int kc = 0; kc < 2; kc++) {
          bf16x8 af = *(const bf16x8*)&x2T[(b * 4096 + j0 + wave * 16 + ln) * 64 + kc * 32 + q * 8];
#pragma unroll
          for (int ist = 0; ist < 4; ist++)
            ps[ist] = __builtin_amdgcn_mfma_f32_16x16x32_bf16(af, b1[b][ist][kc], ps[ist], 0, 0, 0);
        }
#pragma unroll
      for (int ist = 0; ist < 4; ist++) {
        float p0[4], p1[4];
#pragma unroll
        for (int r = 0; r < 4; r++) {
          float e = __expf(-ps[ist][r]);
          p0[r] = __builtin_amdgcn_rcpf(1.f + e);
          p1[r] = 1.f - p0[r];
        }
        uint2 o0 = make_uint2(pk_bf(p0[0], p0[1]), pk_bf(p0[2], p0[3]));
        uint2 o1 = make_uint2(pk_bf(p1[0], p1[1]), pk_bf(p1[2], p1[3]));
        *(uint2*)&Ps[(0 + ist * 16 + ln) * 72 + wave * 16 + q * 4] = o0;
        *(uint2*)&Ps[(64 + ist * 16 + ln) * 72 + wave * 16 + q * 4] = o1;
      }
      __syncthreads();
#pragma unroll
      for (int kc = 0; kc < 2; kc++) {
        bf16x8 af2[2], pb[4];
#pragma unroll
        for (int cst = 0; cst < 2; cst++)
          af2[cst] = *(const bf16x8*)&x2n[(b2 * 64 + (cs2 + cst) * 16 + ln) * 4096 + j0 + kc * 32 + q * 8];
#pragma unroll
        for (int ist = 0; ist < 4; ist++)
          pb[ist] = *(const bf16x8*)&Ps[(b2 * 64 + ist * 16 + ln) * 72 + kc * 32 + q * 8];
#pragma unroll
        for (int cst = 0; cst < 2; cst++)
#pragma unroll
          for (int ist = 0; ist < 4; ist++)
            acc[cst][ist] =
                __builtin_amdgcn_mfma_f32_16x16x32_bf16(af2[cst], pb[ist], acc[cst][ist], 0, 0, 0);
      }
    }
    // epilogue: transpose via LDS, pack bf16, full-128B-line stores
    __syncthreads();
    float* scr = (float*)smem;   // [b*64+c][i pad 68] fp32 = 34816 B
#pragma unroll
    for (int cst = 0; cst < 2; cst++)
#pragma unroll
      for (int ist = 0; ist < 4; ist++)
#pragma unroll
        for (int r = 0; r < 4; r++) {
          int c = (cs2 + cst) * 16 + q * 4 + r;
          scr[(b2 * 64 + c) * 68 + ist * 16 + ln] = acc[cst][ist][r];
        }
    __syncthreads();
#pragma unroll
    for (int rep = 0; rep < 4; rep++) {
      int idx = rep * 256 + t;           // 1024 chunks of 8 u16 (16 B)
      int crow = idx >> 3, ck = idx & 7;
      const float* s = &scr[crow * 68 + ck * 8];
      u32 w0 = pk_bf(s[0], s[1]), w1 = pk_bf(s[2], s[3]);
      u32 w2 = pk_bf(s[4], s[5]), w3 = pk_bf(s[6], s[7]);
      int b = crow >> 6, c = crow & 63;
      u16* dst = &part[(size_t)((jc * 2 + b) * 64 + c) * 4096 + i0 + ck * 8];
      *(uint4*)dst = make_uint4(w0, w1, w2, w3);
    }
  }
  cg::this_grid().sync();

  // ---------------- stage C: out = x1 + sum_jc part[jc] (float2/thread, exact cover) ------
  {
    int id = flat * 256 + t;             // 0..262143, x 2 floats = 524288 = 2*64*4096
    int off = id * 2;
    float2 s = *(const float2*)&x[off];
#pragma unroll
    for (int j = 0; j < 16; j++) {
      u32 pw = *(const u32*)&part[(size_t)j * 524288 + off];
      s.x += __uint_as_float(pw << 16);
      s.y += __uint_as_float(pw & 0xffff0000u);
    }
    *(float2*)&out[off] = s;
  }
}

// ================= fallback (ws too small): R9 atomic path ==================
__global__ __launch_bounds__(256) void conv_fb_kernel(
    const float* __restrict__ x, const float* __restrict__ w,
    const float* __restrict__ bias, u16* __restrict__ x2n, u16* __restrict__ x2T,
    u16* __restrict__ x1T, float* __restrict__ out) {
  __shared__ float xs[64 * 36];
  __shared__ float wl[64 * 64 * 3];
  const int b = blockIdx.x >> 7, jt = blockIdx.x & 127;
  const int t = threadIdx.x;
  for (int idx = t; idx < 64 * 36; idx += 256) {
    int i = idx / 36, p = idx - i * 36;
    int jg = jt * 32 - 1 + p;
    xs[idx] = (jg >= 0 && jg < 4096) ? x[(b * 64 + i) * 4096 + jg] : 0.f;
  }
  for (int idx = t; idx < 64 * 64 * 3; idx += 256) {
    int tap = idx % 3, ci = idx / 3;
    int c = ci >> 6, i = ci & 63;
    wl[(i * 64 + c) * 3 + tap] = w[idx];
  }
  __syncthreads();
  for (int idx = t; idx < 32 * 64; idx += 256) {
    int il = idx >> 6, c = idx & 63;
    float v = xs[c * 36 + il + 1];
    x1T[(b * 4096 + jt * 32 + il) * 64 + c] = f2bf(b ? -v : v);
  }
  for (int idx = t; idx < 64 * 32; idx += 256) {
    int i = idx >> 5, k = idx & 31;
    out[(b * 64 + i) * 4096 + jt * 32 + k] = xs[i * 36 + k + 1];
  }
  const int c = t & 63, jsub = t >> 6;
  float acc[8];
  float bv = bias[c];
#pragma unroll
  for (int k = 0; k < 8; k++) acc[k] = bv;
  for (int i = 0; i < 64; i++) {
    float w0 = wl[(i * 64 + c) * 3 + 0];
    float w1 = wl[(i * 64 + c) * 3 + 1];
    float w2 = wl[(i * 64 + c) * 3 + 2];
    const float* xr = &xs[i * 36 + jsub * 8];
#pragma unroll
    for (int k = 0; k < 8; k++)
      acc[k] += w0 * xr[k] + w1 * xr[k + 2] + w2 * xr[k + 4];
  }
#pragma unroll
  for (int k = 0; k < 8; k++) {
    int jg = jt * 32 + jsub * 8 + k;
    u16 hv = f2bf(jg < NJ ? acc[k] : 0.f);
    x2n[(b * 64 + c) * 4096 + jg] = hv;
    x2T[(b * 4096 + jg) * 64 + c] = hv;
  }
}

__global__ __launch_bounds__(256, 4) void fused_fb_kernel(
    const u16* __restrict__ x1T_g, const u16* __restrict__ x2n_g,
    const u16* __restrict__ x2T_g, float* __restrict__ out) {
  __shared__ u16 P[2][2 * 64 * 72];
  const int t = threadIdx.x;
  const int wave = t >> 6, lane = t & 63;
  const int q = lane >> 4, ln = lane & 15;
  const int i0 = blockIdx.x * 64;
  const int jc = blockIdx.y;
  bf16x8 b1[2][4][2];
#pragma unroll
  for (int b = 0; b < 2; b++)
#pragma unroll
    for (int ist = 0; ist < 4; ist++)
#pragma unroll
      for (int kc = 0; kc < 2; kc++)
        b1[b][ist][kc] = *(const bf16x8*)&x1T_g[(b * 4096 + i0 + ist * 16 + ln) * 64 + kc * 32 + q * 8];
  f32x4 acc[2][4];
#pragma unroll
  for (int a = 0; a < 2; a++)
#pragma unroll
    for (int bq = 0; bq < 4; bq++) acc[a][bq] = (f32x4){0.f, 0.f, 0.f, 0.f};
  const int b2 = wave >> 1, cs2 = (wave & 1) * 2;
  for (int jt = jc * 4; jt < jc * 4 + 4; jt++) {
    const int j0 = jt * 64;
    u16* Ps = P[jt & 1];
    f32x4 ps[4];
#pragma unroll
    for (int ist = 0; ist < 4; ist++) ps[ist] = (f32x4){0.f, 0.f, 0.f, 0.f};
#pragma unroll
    for (int b = 0; b < 2; b++)
#pragma unroll
      for (int kc = 0; kc < 2; kc++) {
        bf16x8 af = *(const bf16x8*)&x2T_g[(b * 4096 + j0 + wave * 16 + ln) * 64 + kc * 32 + q * 8];
#pragma unroll
        for (int ist = 0; ist < 4; ist++)
          ps[ist] = __builtin_amdgcn_mfma_f32_16x16x32_bf16(af, b1[b][ist][kc], ps[ist], 0, 0, 0);
      }
#pragma unroll
    for (int ist = 0; ist < 4; ist++) {
      float p0[4], p1[4];
#pragma unroll
      for (int r = 0; r < 4; r++) {
        float e = __expf(-ps[ist][r]);
        p0[r] = __builtin_amdgcn_rcpf(1.f + e);
        p1[r] = 1.f - p0[r];
      }
      uint2 o0 = make_uint2(pk_bf(p0[0], p0[1]), pk_bf(p0[2], p0[3]));
      uint2 o1 = make_uint2(pk_bf(p1[0], p1[1]), pk_bf(p1[2], p1[3]));
      *(uint2*)&Ps[(0 + ist * 16 + ln) * 72 + wave * 16 + q * 4] = o0;
      *(uint2*)&Ps[(64 + ist * 16 + ln) * 72 + wave * 16 + q * 4] = o1;
    }
    __syncthreads();
#pragma unroll
    for (int kc = 0; kc < 2; kc++) {
      bf16x8 af2[2], pb[4];
#pragma unroll
      for (int cst = 0; cst < 2; cst++)
        af2[cst] = *(const bf16x8*)&x2n_g[(b2 * 64 + (cs2 + cst) * 16 + ln) * 4096 + j0 + kc * 32 + q * 8];
#pragma unroll
      for (int ist = 0; ist < 4; ist++)
        pb[ist] = *(const bf16x8*)&Ps[(b2 * 64 + ist * 16 + ln) * 72 + kc * 32 + q * 8];
#pragma unroll
      for (int cst = 0; cst < 2; cst++)
#pragma unroll
        for (int ist = 0; ist < 4; ist++)
          acc[cst][ist] =
              __builtin_amdgcn_mfma_f32_16x16x32_bf16(af2[cst], pb[ist], acc[cst][ist], 0, 0, 0);
    }
  }
#pragma unroll
  for (int cst = 0; cst < 2; cst++)
#pragma unroll
    for (int ist = 0; ist < 4; ist++)
#pragma unroll
      for (int r = 0; r < 4; r++) {
        int c = (cs2 + cst) * 16 + q * 4 + r;
        int ii = i0 + ist * 16 + ln;
        unsafeAtomicAdd(&out[(b2 * 64 + c) * 4096 + ii], acc[cst][ist][r]);
      }
}

extern "C" void kernel_launch(void* const* d_in, const int* in_sizes, int n_in,
                              void* d_out, int out_size, void* d_ws, size_t ws_size,
                              hipStream_t stream) {
  const float* x = (const float*)d_in[0];
  const float* w = (const float*)d_in[1];
  const float* bias = (const float*)d_in[2];
  float* out = (float*)d_out;
  u16* x2n = (u16*)d_ws;                   // [2][64][4096] bf16 = 1 MB
  u16* x2T = x2n + 2 * 64 * 4096;          // [2][4096][64] bf16 = 1 MB
  u16* x1T = x2T + 2 * 64 * 4096;          // [2][4096][64] bf16 = 1 MB (b=1 negated)
  u16* part = x1T + 2 * 64 * 4096;         // [16][2][64][4096] bf16 = 16 MB

  const size_t need = 3u * (2 * 64 * 4096 * 2) + 16u * 2 * 64 * 4096 * 2;
  if (ws_size >= need) {
    void* args[] = {(void*)&x, (void*)&w, (void*)&bias, (void*)&x2n,
                    (void*)&x2T, (void*)&x1T, (void*)&part, (void*)&out};
    hipError_t e = hipLaunchCooperativeKernel((const void*)mono_kernel, dim3(64, 16),
                                              dim3(256), args, 0, stream);
    if (e == hipSuccess) return;
    // fall through to non-coop path on launch failure
  }
  conv_fb_kernel<<<256, 256, 0, stream>>>(x, w, bias, x2n, x2T, x1T, out);
  dim3 grid(64, 16);
  fused_fb_kernel<<<grid, 256, 0, stream>>>(x1T, x2n, x2T, out);
}

// Round 11
// 110.434 us; speedup vs baseline: 3.0929x; 3.0929x over previous
//
#include <hip/hip_runtime.h>

typedef unsigned short u16;
typedef unsigned int u32;
typedef __attribute__((ext_vector_type(8))) short bf16x8;
typedef __attribute__((ext_vector_type(4))) float f32x4;

#define NJ 4094

__device__ __forceinline__ u16 f2bf(float f) {
  union { float f; unsigned u; } v;
  v.f = f;
  unsigned r = v.u + 0x7fffu + ((v.u >> 16) & 1u);
  return (u16)(r >> 16);
}

// pack hi16(a),hi16(b) -> u32 (a in low half), +0x8000 round-half-up pre-added
__device__ __forceinline__ u32 pk_bf(float a, float b) {
  u32 ua = __float_as_uint(a) + 0x8000u;
  u32 ub = __float_as_uint(b) + 0x8000u;
  return __builtin_amdgcn_perm(ub, ua, 0x07060302u);
}

// ---------------- dilated conv1d -> x2 (bf16, two layouts, j zero-padded to 4096)
// + x1T bf16 [b][i][c] with b=1 pre-negated. 256 blocks = all CUs busy.
// WRITE_OUT: also out = x1 (atomic fallback path only)
template <bool WRITE_OUT>
__global__ __launch_bounds__(256) void conv_kernel(
    const float* __restrict__ x, const float* __restrict__ w,
    const float* __restrict__ bias, u16* __restrict__ x2n, u16* __restrict__ x2T,
    u16* __restrict__ x1T, float* __restrict__ out) {
  __shared__ float xs[64 * 36];       // [in_ch][36 window: j-1 .. j+34]
  __shared__ float wl[64 * 64 * 3];   // [in_ch][out_ch][tap]
  const int b = blockIdx.x >> 7, jt = blockIdx.x & 127;
  const int t = threadIdx.x;
  for (int idx = t; idx < 64 * 36; idx += 256) {
    int i = idx / 36, p = idx - i * 36;
    int jg = jt * 32 - 1 + p;
    xs[idx] = (jg >= 0 && jg < 4096) ? x[(b * 64 + i) * 4096 + jg] : 0.f;
  }
  for (int idx = t; idx < 64 * 64 * 3; idx += 256) {
    int tap = idx % 3, ci = idx / 3;
    int c = ci >> 6, i = ci & 63;
    wl[(i * 64 + c) * 3 + tap] = w[idx];
  }
  __syncthreads();
  // x1T: [b][i][c] bf16, b=1 negated (folds S0-S1 into one MFMA chain)
  for (int idx = t; idx < 32 * 64; idx += 256) {
    int il = idx >> 6, c = idx & 63;
    float v = xs[c * 36 + il + 1];
    x1T[(b * 4096 + jt * 32 + il) * 64 + c] = f2bf(b ? -v : v);
  }
  if (WRITE_OUT) {
    for (int idx = t; idx < 64 * 32; idx += 256) {
      int i = idx >> 5, k = idx & 31;
      out[(b * 64 + i) * 4096 + jt * 32 + k] = xs[i * 36 + k + 1];
    }
  }
  const int c = t & 63, jsub = t >> 6;   // each thread: 8 consecutive j
  float acc[8];
  float bv = bias[c];
#pragma unroll
  for (int k = 0; k < 8; k++) acc[k] = bv;
  for (int i = 0; i < 64; i++) {
    float w0 = wl[(i * 64 + c) * 3 + 0];
    float w1 = wl[(i * 64 + c) * 3 + 1];
    float w2 = wl[(i * 64 + c) * 3 + 2];
    const float* xr = &xs[i * 36 + jsub * 8];
#pragma unroll
    for (int k = 0; k < 8; k++)
      acc[k] += w0 * xr[k] + w1 * xr[k + 2] + w2 * xr[k + 4];
  }
#pragma unroll
  for (int k = 0; k < 8; k++) {
    int jg = jt * 32 + jsub * 8 + k;
    u16 hv = f2bf(jg < NJ ? acc[k] : 0.f);   // zero-pad j=4094,4095
    x2n[(b * 64 + c) * 4096 + jg] = hv;
    x2T[(b * 4096 + jg) * 64 + c] = hv;
  }
}

// ---------------- fused kernel (R9 loop structure — do NOT re-add the unroll+prefetch
// pipeline: R5/R7 spill signature FETCH 9->55 MB, WRITE 32->101 MB; no coop grid.sync:
// R10 showed 256 us). Epilogue packs partials to bf16 (R10-validated, absmax unchanged):
// halves partial write+read traffic vs fp32.
template <bool ATOMIC>
__global__ __launch_bounds__(256, 4) void fused_kernel(
    const u16* __restrict__ x1T_g, const u16* __restrict__ x2n_g,
    const u16* __restrict__ x2T_g, u16* __restrict__ part_g,
    float* __restrict__ out) {
  __shared__ u16 P[2][2 * 64 * 72];   // [buf][b*64+i][j64 pad72]; reused by epilogue
  const int t = threadIdx.x;
  const int wave = t >> 6, lane = t & 63;
  const int q = lane >> 4, ln = lane & 15;
  const int i0 = blockIdx.x * 64;
  const int jc = blockIdx.y;

  // x1 B-frags for all 4 i-subtiles, both batches, straight from global bf16
  bf16x8 b1[2][4][2];
#pragma unroll
  for (int b = 0; b < 2; b++)
#pragma unroll
    for (int ist = 0; ist < 4; ist++)
#pragma unroll
      for (int kc = 0; kc < 2; kc++)
        b1[b][ist][kc] = *(const bf16x8*)&x1T_g[(b * 4096 + i0 + ist * 16 + ln) * 64 + kc * 32 + q * 8];

  f32x4 acc[2][4];
#pragma unroll
  for (int a = 0; a < 2; a++)
#pragma unroll
    for (int bq = 0; bq < 4; bq++) acc[a][bq] = (f32x4){0.f, 0.f, 0.f, 0.f};

  const int b2 = wave >> 1, cs2 = (wave & 1) * 2;

  for (int jt = jc * 4; jt < jc * 4 + 4; jt++) {
    const int j0 = jt * 64;
    u16* Ps = P[jt & 1];
    // ---- phase 1: wave's 16-j strip x all 64 i; b=1 pre-negated -> acc = S0-S1
    f32x4 ps[4];
#pragma unroll
    for (int ist = 0; ist < 4; ist++) ps[ist] = (f32x4){0.f, 0.f, 0.f, 0.f};
#pragma unroll
    for (int b = 0; b < 2; b++)
#pragma unroll
      for (int kc = 0; kc < 2; kc++) {
        bf16x8 af = *(const bf16x8*)&x2T_g[(b * 4096 + j0 + wave * 16 + ln) * 64 + kc * 32 + q * 8];
#pragma unroll
        for (int ist = 0; ist < 4; ist++)
          ps[ist] = __builtin_amdgcn_mfma_f32_16x16x32_bf16(af, b1[b][ist][kc], ps[ist], 0, 0, 0);
      }
    // ---- sigmoid; lane rows j=wave*16+q*4+r, col i=ist*16+ln; packed b64 LDS writes
#pragma unroll
    for (int ist = 0; ist < 4; ist++) {
      float p0[4], p1[4];
#pragma unroll
      for (int r = 0; r < 4; r++) {
        float e = __expf(-ps[ist][r]);
        p0[r] = __builtin_amdgcn_rcpf(1.f + e);
        p1[r] = 1.f - p0[r];
      }
      uint2 o0 = make_uint2(pk_bf(p0[0], p0[1]), pk_bf(p0[2], p0[3]));
      uint2 o1 = make_uint2(pk_bf(p1[0], p1[1]), pk_bf(p1[2], p1[3]));
      *(uint2*)&Ps[(0 + ist * 16 + ln) * 72 + wave * 16 + q * 4] = o0;
      *(uint2*)&Ps[(64 + ist * 16 + ln) * 72 + wave * 16 + q * 4] = o1;
    }
    __syncthreads();   // only barrier per j-tile (dbuf covers WAR)
    // ---- phase 2: D[m=c16][n=i16], A = x2n rows (16B global), B = P rows (ds_read_b128)
#pragma unroll
    for (int kc = 0; kc < 2; kc++) {
      bf16x8 af2[2], pb[4];
#pragma unroll
      for (int cst = 0; cst < 2; cst++)
        af2[cst] = *(const bf16x8*)&x2n_g[(b2 * 64 + (cs2 + cst) * 16 + ln) * 4096 + j0 + kc * 32 + q * 8];
#pragma unroll
      for (int ist = 0; ist < 4; ist++)
        pb[ist] = *(const bf16x8*)&Ps[(b2 * 64 + ist * 16 + ln) * 72 + kc * 32 + q * 8];
#pragma unroll
      for (int cst = 0; cst < 2; cst++)
#pragma unroll
        for (int ist = 0; ist < 4; ist++)
          acc[cst][ist] =
              __builtin_amdgcn_mfma_f32_16x16x32_bf16(af2[cst], pb[ist], acc[cst][ist], 0, 0, 0);
    }
  }
  if (ATOMIC) {
#pragma unroll
    for (int cst = 0; cst < 2; cst++)
#pragma unroll
      for (int ist = 0; ist < 4; ist++)
#pragma unroll
        for (int r = 0; r < 4; r++) {
          int c = (cs2 + cst) * 16 + q * 4 + r;
          int ii = i0 + ist * 16 + ln;
          unsafeAtomicAdd(&out[(b2 * 64 + c) * 4096 + ii], acc[cst][ist][r]);
        }
  } else {
    // ---- epilogue: transpose via LDS, pack bf16, full-128B-line uint4 stores
    __syncthreads();                       // P reads of last tile done
    float* scr = (float*)P;                // [b*64 + c][i pad 68] fp32 = 34816 B
#pragma unroll
    for (int cst = 0; cst < 2; cst++)
#pragma unroll
      for (int ist = 0; ist < 4; ist++)
#pragma unroll
        for (int r = 0; r < 4; r++) {
          int c = (cs2 + cst) * 16 + q * 4 + r;
          scr[(b2 * 64 + c) * 68 + ist * 16 + ln] = acc[cst][ist][r];   // 2-way alias: free
        }
    __syncthreads();
#pragma unroll
    for (int rep = 0; rep < 4; rep++) {
      int idx = rep * 256 + t;             // 1024 chunks of 8 bf16 (16 B)
      int crow = idx >> 3, ck = idx & 7;   // crow = b*64+c
      const float* s = &scr[crow * 68 + ck * 8];
      u32 w0 = pk_bf(s[0], s[1]), w1 = pk_bf(s[2], s[3]);
      u32 w2 = pk_bf(s[4], s[5]), w3 = pk_bf(s[6], s[7]);
      int b = crow >> 6, c = crow & 63;
      u16* dst = &part_g[(size_t)((jc * 2 + b) * 64 + c) * 4096 + i0 + ck * 8];
      *(uint4*)dst = make_uint4(w0, w1, w2, w3);
    }
  }
}

// ---------------- out = x1 + sum_jc part[jc] (bf16 partials, float4 x/out) ----------------
__global__ __launch_bounds__(256) void reduce_kernel(
    const float* __restrict__ x, const u16* __restrict__ part,
    float* __restrict__ out) {
  int off = (blockIdx.x * 256 + threadIdx.x) * 4;   // over 524288 floats
  float4 s = *(const float4*)&x[off];
#pragma unroll
  for (int j = 0; j < 16; j++) {
    uint2 pw = *(const uint2*)&part[(size_t)j * 524288 + off];
    s.x += __uint_as_float(pw.x << 16);
    s.y += __uint_as_float(pw.x & 0xffff0000u);
    s.z += __uint_as_float(pw.y << 16);
    s.w += __uint_as_float(pw.y & 0xffff0000u);
  }
  *(float4*)&out[off] = s;
}

extern "C" void kernel_launch(void* const* d_in, const int* in_sizes, int n_in,
                              void* d_out, int out_size, void* d_ws, size_t ws_size,
                              hipStream_t stream) {
  const float* x = (const float*)d_in[0];
  const float* w = (const float*)d_in[1];
  const float* bias = (const float*)d_in[2];
  float* out = (float*)d_out;
  u16* x2n = (u16*)d_ws;                   // [2][64][4096] bf16 = 1 MB
  u16* x2T = x2n + 2 * 64 * 4096;          // [2][4096][64] bf16 = 1 MB
  u16* x1T = x2T + 2 * 64 * 4096;          // [2][4096][64] bf16 = 1 MB (b=1 negated)
  u16* part = x1T + 2 * 64 * 4096;         // [16][2][64][4096] bf16 = 16 MB

  const size_t need = 3u * (2 * 64 * 4096 * 2) + 16u * 2 * 64 * 4096 * 2;
  dim3 grid(64, 16);
  if (ws_size >= need) {
    conv_kernel<false><<<256, 256, 0, stream>>>(x, w, bias, x2n, x2T, x1T, out);
    fused_kernel<false><<<grid, 256, 0, stream>>>(x1T, x2n, x2T, part, out);
    reduce_kernel<<<512, 256, 0, stream>>>(x, part, out);
  } else {
    conv_kernel<true><<<256, 256, 0, stream>>>(x, w, bias, x2n, x2T, x1T, out);
    fused_kernel<true><<<grid, 256, 0, stream>>>(x1T, x2n, x2T, nullptr, out);
  }
}